// Round 1
// baseline (256.423 us; speedup 1.0000x reference)
//
#include <hip/hip_runtime.h>
#include <hip/hip_bf16.h>

// B=2, S=2048, D=1024, H=16, dk=64. INPUTS FP32, OUTPUT FP32. M = 4096 rows.
// ROUND 19: KV-SPLIT attention — 4 waves per block share one (strip, bh) pair,
// wave w handles KV tiles j = w, w+4, ... (fixed-max softmax => partial
// (oacc, l) are exactly additive). Cuts the longest serial chain 32 -> 8
// iterations and load-balances the grid; epilogue combines partials in LDS.

typedef __bf16 bf16x8 __attribute__((ext_vector_type(8)));
typedef float f32x4 __attribute__((ext_vector_type(4)));

#define LOG2E 1.4426950408889634f
#define SMAX 16.0f

__device__ __forceinline__ ushort f2bf(float f) {
  __hip_bfloat16 h = __float2bfloat16(f);
  return __builtin_bit_cast(ushort, h);
}

__device__ __forceinline__ uint pack2(float a, float b) {
  return (uint)f2bf(a) | ((uint)f2bf(b) << 16);
}

// truncating bf16x2 pack in one v_perm_b32
__device__ __forceinline__ uint pack2t(float a, float b) {
  return __builtin_amdgcn_perm(__builtin_bit_cast(uint, b),
                               __builtin_bit_cast(uint, a), 0x07060302u);
}

#define CBAR() __asm__ __volatile__("" ::: "memory")

__device__ __forceinline__ void gl2lds16(const ushort* g, ushort* l) {
  __builtin_amdgcn_global_load_lds(
      (const __attribute__((address_space(1))) void*)g,
      (__attribute__((address_space(3))) void*)l, 16, 0, 0);
}

// ------------------------------------------------------------ fp32 -> bf16
__global__ __launch_bounds__(256) void conv_bf16(const float* __restrict__ src,
                                                 ushort* __restrict__ dst,
                                                 int n8) {
  int i = blockIdx.x * 256 + threadIdx.x;
  if (i >= n8) return;
  const float4* s = (const float4*)src + (long)i * 2;
  float4 a = s[0], b = s[1];
  uint4 pk = {pack2(a.x, a.y), pack2(a.z, a.w), pack2(b.x, b.y), pack2(b.z, b.w)};
  ((uint4*)dst)[i] = pk;
}

// ---------------------------------------------------------------- GEMM (NT)
// (unchanged — validated)
__global__ __launch_bounds__(256) void gemm_bt(
    const ushort* __restrict__ A, const ushort* __restrict__ B, int nbn,
    ushort* __restrict__ qb, ushort* __restrict__ kb, ushort* __restrict__ vb,
    float* __restrict__ Cout, int epi) {
  __shared__ __align__(16) ushort As[128 * 64];
  __shared__ __align__(16) ushort Bs[128 * 64];
  const int tid = threadIdx.x;
  const int w = tid >> 6, lane = tid & 63, quad = lane >> 4, lc = lane & 15;
  const int bid = blockIdx.x;
  const int bm = bid / nbn, bn = bid % nbn;
  const int wm = (w & 1) * 64, wn = (w >> 1) * 64;

  f32x4 acc[4][4] = {};

  const ushort* Ag = A + (long)bm * 131072;
  const ushort* Bg = B + (long)bn * 131072;

  for (int k0 = 0; k0 < 1024; k0 += 64) {
    __syncthreads();
    for (int i = 0; i < 4; ++i) {
      int u = i * 256 + tid;
      int row = u >> 3, ch = u & 7;
      gl2lds16(Ag + row * 1024 + k0 + ch * 8, &As[(i * 256 + w * 64) * 8]);
      gl2lds16(Bg + row * 1024 + k0 + ch * 8, &Bs[(i * 256 + w * 64) * 8]);
    }
    __builtin_amdgcn_s_waitcnt(0);
    __syncthreads();
    for (int kc = 0; kc < 2; ++kc) {
      bf16x8 af[4], bfr[4];
      for (int t = 0; t < 4; ++t)
        af[t] = *(const bf16x8*)&As[(wm + t * 16 + lc) * 64 + kc * 32 + quad * 8];
      for (int t = 0; t < 4; ++t)
        bfr[t] = *(const bf16x8*)&Bs[(wn + t * 16 + lc) * 64 + kc * 32 + quad * 8];
      for (int rt = 0; rt < 4; ++rt)
        for (int ct = 0; ct < 4; ++ct)
          acc[rt][ct] = __builtin_amdgcn_mfma_f32_16x16x32_bf16(
              af[rt], bfr[ct], acc[rt][ct], 0, 0, 0);
    }
  }

  const int row0 = bm * 128 + wm;
  if (epi == 0) {
    const int e0 = bn * 128;
    const int g = e0 >> 10;
    const int h = ((e0 & 1023) + wn) >> 6;
    const float qs = (g == 0) ? 0.125f * LOG2E : 1.0f;
    ushort* dst = (g == 0) ? qb : ((g == 1) ? kb : vb);
    const float ang = powf(1e-4f, (float)lc * (1.0f / 15.0f));
    for (int rt = 0; rt < 4; ++rt) {
      for (int r = 0; r < 4; ++r) {
        int m = row0 + rt * 16 + quad * 4 + r;
        int srow = m & 2047;
        int b = m >> 11;
        if (g < 2) {
          float theta = (float)srow * ang;
          float sn, c;
          sincosf(theta, &sn, &c);
          float x1 = acc[rt][0][r], x2 = acc[rt][2][r];
          acc[rt][0][r] = x1 * c - x2 * sn;
          acc[rt][2][r] = x1 * sn + x2 * c;
        }
        ushort* drow = dst + (((long)b * 16 + h) * 2048 + srow) * 64;
        for (int ct = 0; ct < 4; ++ct)
          drow[ct * 16 + lc] = f2bf(acc[rt][ct][r] * qs);
      }
    }
  } else {
    for (int rt = 0; rt < 4; ++rt)
      for (int r = 0; r < 4; ++r) {
        int m = row0 + rt * 16 + quad * 4 + r;
        float* drow = Cout + (long)m * 1024 + bn * 128 + wn;
        for (int ct = 0; ct < 4; ++ct)
          drow[ct * 16 + lc] = acc[rt][ct][r];
      }
  }
}

// ----------------------------------------------------------- V transpose
__global__ __launch_bounds__(256) void vtrans(const ushort* __restrict__ vb,
                                              ushort* __restrict__ vt) {
  __shared__ __align__(16) ushort T[64 * 72];
  const int tid = threadIdx.x, sc = blockIdx.x, bh = blockIdx.y;
  const ushort* src = vb + ((long)bh * 2048 + sc * 64) * 64;
  for (int i = 0; i < 2; ++i) {
    int u = i * 256 + tid;
    int row = u >> 3, ch = u & 7;
    uint4 vv = *(const uint4*)&src[row * 64 + ch * 8];
    const ushort* e = (const ushort*)&vv;
    for (int t = 0; t < 8; ++t) T[(ch * 8 + t) * 72 + row] = e[t];
  }
  __syncthreads();
  for (int i = 0; i < 2; ++i) {
    int u = i * 256 + tid;
    int d = u >> 3, ch = u & 7;
    uint4 vv = *(const uint4*)&T[d * 72 + ch * 8];
    *(uint4*)&vt[((long)bh * 64 + d) * 2048 + sc * 64 + ch * 8] = vv;
  }
}

// ---------------------------------------------------------------- attention
// FOUR WAVES PER BLOCK, one (strip, bh) pair per block. Wave w handles KV
// tiles j = w, w+4, ... (register-prefetched one iter ahead, pointer-stepped
// addressing). Fixed-max softmax => partials are additive; combine in LDS.
__global__ __launch_bounds__(256) void attn_kernel(
    const ushort* __restrict__ qb, const ushort* __restrict__ kb,
    const ushort* __restrict__ vt, ushort* __restrict__ out) {
  __shared__ __align__(16) ushort PswAll[4][2][32 * 64];  // per-wave P buffers
  __shared__ float lredL[4][32];                          // per-wave l partials
  const int tid = threadIdx.x;
  const int w = tid >> 6;                       // wave id 0..3
  const int lane = tid & 63;
  const int quad = lane >> 4, lc = lane & 15, l7 = lc & 7;
  const int bid = blockIdx.x;                   // 0..2047
  const int s = 63 - (bid >> 5);                // strip, big-work first
  const int bh = bid & 31;
  const int bidx = bh >> 4, h = bh & 15;
  const int qtbase = s * 32;
  const int jmax = s >> 1;
  const int cnt = (w <= jmax) ? (((jmax - w) >> 2) + 1) : 0;
  const bool maskw = ((jmax & 3) == w);         // this wave owns the causal tile
  const int rowoff = (s & 1) * 32;

  f32x4 oacc[4][2] = {};
  float l_lane[2] = {0.0f, 0.0f};

  if (cnt > 0) {
    bf16x8 qf[2][2];
    for (int kc = 0; kc < 2; ++kc)
      for (int q2 = 0; q2 < 2; ++q2)
        qf[kc][q2] = *(const bf16x8*)&qb[((long)bh * 2048 + qtbase + q2 * 16 + lc) * 64 +
                                         kc * 32 + quad * 8];

    // per-lane fragment offsets (constant within the loop)
    const int koff = lc * 64 + quad * 8;
    const int voff = lc * 2048 + quad * 8;
    const ushort* Kp = kb + (long)bh * 131072 + w * 4096;   // tile w of K
    const ushort* Vp = vt + (long)bh * 131072 + w * 64;     // tile w of Vt

    // prologue: load tile j = w
    bf16x8 kfc[2][4], vfc[2][4];
    for (int kc = 0; kc < 2; ++kc)
      for (int t = 0; t < 4; ++t) {
        kfc[kc][t] = *(const bf16x8*)&Kp[t * 1024 + kc * 32 + koff];
        vfc[kc][t] = *(const bf16x8*)&Vp[t * 32768 + kc * 32 + voff];
      }

    for (int i = 0; i < cnt; ++i) {
      ushort* Psw = PswAll[w][i & 1];
      const bool last = (i == cnt - 1);
      // prefetch next owned tile (clamped: reload current on last iter)
      const ushort* Kn = last ? Kp : (Kp + 4 * 4096);
      const ushort* Vn = last ? Vp : (Vp + 4 * 64);
      bf16x8 kfn[2][4], vfn[2][4];
      for (int kc = 0; kc < 2; ++kc)
        for (int t = 0; t < 4; ++t) {
          kfn[kc][t] = *(const bf16x8*)&Kn[t * 1024 + kc * 32 + koff];
          vfn[kc][t] = *(const bf16x8*)&Vn[t * 32768 + kc * 32 + voff];
        }

      f32x4 sacc[4][2] = {};
      for (int kc = 0; kc < 2; ++kc)
        for (int kt = 0; kt < 4; ++kt)
          for (int q2 = 0; q2 < 2; ++q2)
            sacc[kt][q2] = __builtin_amdgcn_mfma_f32_16x16x32_bf16(
                kfc[kc][kt], qf[kc][q2], sacc[kt][q2], 0, 0, 0);

      if (last && maskw) {  // causal partial tile (j == jmax)
        for (int kt = 0; kt < 4; ++kt)
          for (int q2 = 0; q2 < 2; ++q2) {
            int rowrel = rowoff + q2 * 16 + lc;
            for (int r = 0; r < 4; ++r)
              if (kt * 16 + quad * 4 + r > rowrel) sacc[kt][q2][r] = -1.0e30f;
          }
      }
      for (int q2 = 0; q2 < 2; ++q2) {
        float p[4][4];
        float rs = 0.0f;
        for (int kt = 0; kt < 4; ++kt)
          for (int r = 0; r < 4; ++r) {
            p[kt][r] = exp2f(sacc[kt][q2][r] - SMAX);
            rs += p[kt][r];
          }
        l_lane[q2] += rs;
        for (int kt = 0; kt < 4; ++kt) {
          uint2 pk = {pack2t(p[kt][0], p[kt][1]), pack2t(p[kt][2], p[kt][3])};
          *(uint2*)&Psw[(q2 * 16 + lc) * 64 + (((kt * 2 + (quad >> 1)) ^ l7) << 3) +
                        ((quad & 1) << 2)] = pk;
        }
      }
      CBAR();  // compiler-only: P writes before P reads (HW DS in-order per wave)
      for (int kc = 0; kc < 2; ++kc) {
        bf16x8 pf[2];
        for (int q2 = 0; q2 < 2; ++q2)
          pf[q2] = *(const bf16x8*)&Psw[(q2 * 16 + lc) * 64 +
                                        (((kc * 4 + quad) ^ l7) << 3)];
        for (int mt = 0; mt < 4; ++mt)
          for (int q2 = 0; q2 < 2; ++q2)
            oacc[mt][q2] = __builtin_amdgcn_mfma_f32_16x16x32_bf16(
                vfc[kc][mt], pf[q2], oacc[mt][q2], 0, 0, 0);
      }
      // rotate prefetched tiles into current; step pointers
      for (int kc = 0; kc < 2; ++kc)
        for (int t = 0; t < 4; ++t) {
          kfc[kc][t] = kfn[kc][t];
          vfc[kc][t] = vfn[kc][t];
        }
      Kp = Kn;
      Vp = Vn;
    }
  }

  // ---------------- epilogue: additive combine of 4 wave-partials ----------
  float l_[2];
  for (int q2 = 0; q2 < 2; ++q2) {
    float rs = l_lane[q2];
    rs += __shfl_xor(rs, 16, 64);
    rs += __shfl_xor(rs, 32, 64);
    l_[q2] = rs;
  }
  CBAR();
  // write this wave's oacc partial into its own P region (conflict-free layout:
  // [mt*2+q2][lane] f32x4 -> 16B stride between lanes)
  {
    float* OP = (float*)PswAll[w];
    for (int mt = 0; mt < 4; ++mt)
      for (int q2 = 0; q2 < 2; ++q2)
        *(f32x4*)&OP[(mt * 2 + q2) * 256 + lane * 4] = oacc[mt][q2];
    if (quad == 0) {
      lredL[w][lc] = l_[0];
      lredL[w][16 + lc] = l_[1];
    }
  }
  __syncthreads();
  // wave w reduces the mt == w quarter across the 4 source waves
  f32x4 osum[2] = {};
  float lt[2] = {0.0f, 0.0f};
  for (int sw = 0; sw < 4; ++sw) {
    const float* SP = (const float*)PswAll[sw];
    for (int q2 = 0; q2 < 2; ++q2) {
      osum[q2] += *(const f32x4*)&SP[(w * 2 + q2) * 256 + lane * 4];
      lt[q2] += lredL[sw][q2 * 16 + lc];
    }
  }
  __syncthreads();  // everyone done reading partials; reuse LDS for staging
  ushort* St = (ushort*)PswAll;  // 4 KiB bf16 staging, swizzled rows
  for (int q2 = 0; q2 < 2; ++q2) {
    float linv = 1.0f / lt[q2];
    uint2 pk = {pack2(osum[q2][0] * linv, osum[q2][1] * linv),
                pack2(osum[q2][2] * linv, osum[q2][3] * linv)};
    *(uint2*)&St[(q2 * 16 + lc) * 64 + (((w * 2 + (quad >> 1)) ^ l7) << 3) +
                 ((quad & 1) << 2)] = pk;
  }
  __syncthreads();
  {
    int r2 = tid >> 3, c8 = tid & 7;
    long mrow = (long)bidx * 2048 + qtbase + r2;
    uint4 vv = *(const uint4*)&St[r2 * 64 + ((c8 ^ (r2 & 7)) << 3)];
    *(uint4*)&out[mrow * 1024 + h * 64 + c8 * 8] = vv;
  }
}

extern "C" void kernel_launch(void* const* d_in, const int* in_sizes, int n_in,
                              void* d_out, int out_size, void* d_ws, size_t ws_size,
                              hipStream_t stream) {
  const float* x = nullptr;     // 4194304 elems
  const float* Wqkv = nullptr;  // 3145728 elems
  const float* Wo = nullptr;    // 1048576 elems
  for (int i = 0; i < n_in; ++i) {
    if (in_sizes[i] == 4194304) x = (const float*)d_in[i];
    else if (in_sizes[i] == 3145728) Wqkv = (const float*)d_in[i];
    else if (in_sizes[i] == 1048576) Wo = (const float*)d_in[i];
  }
  float* out = (float*)d_out;  // [4096,1024] fp32 (16 MiB)

  // Workspace (32 MiB) + d_out-as-scratch timeline (same as r13):
  ushort* qbuf = (ushort*)d_ws;
  ushort* kbuf = qbuf + 4194304;
  ushort* vbuf = kbuf + 4194304;
  ushort* vtb  = vbuf + 4194304;
  ushort* wqkvh = vtb;                 // [24..30) before vtrans
  ushort* woh  = qbuf;                 // [0..2) after attn
  ushort* ao   = vbuf;                 // aliases vbuf
  ushort* xh   = (ushort*)d_out;       // x_bf16 in d_out scratch

  conv_bf16<<<2048, 256, 0, stream>>>(x, xh, 524288);
  conv_bf16<<<1536, 256, 0, stream>>>(Wqkv, wqkvh, 393216);
  gemm_bt<<<768, 256, 0, stream>>>(xh, wqkvh, 24, qbuf, kbuf, vbuf, nullptr, 0);
  vtrans<<<dim3(32, 32), 256, 0, stream>>>(vbuf, vtb);
  attn_kernel<<<2048, 256, 0, stream>>>(qbuf, kbuf, vtb, ao);
  conv_bf16<<<512, 256, 0, stream>>>(Wo, woh, 131072);
  gemm_bt<<<256, 256, 0, stream>>>(ao, woh, 8, nullptr, nullptr, nullptr, out, 1);
}

// Round 2
// 240.998 us; speedup vs baseline: 1.0640x; 1.0640x over previous
//
#include <hip/hip_runtime.h>
#include <hip/hip_bf16.h>

// B=2, S=2048, D=1024, H=16, dk=64. INPUTS FP32, OUTPUT FP32. M = 4096 rows.
// ROUND 20: r18 single-wave attn structure (r19 KV-split regressed: blocks
// queued at 3-resident/CU instead of whole-grid-resident). VALU diet:
//   - raw v_exp_f32 (1 trans inst) instead of ocml exp2f (~6 VALU insts)
//   - fixed-max softmax shift dropped entirely (constant cancels in p/sum(p))
//   - 2x-unrolled j-loop with A/B register ping-pong (kills 64 v_mov/iter)

typedef __bf16 bf16x8 __attribute__((ext_vector_type(8)));
typedef float f32x4 __attribute__((ext_vector_type(4)));

#define LOG2E 1.4426950408889634f

__device__ __forceinline__ ushort f2bf(float f) {
  __hip_bfloat16 h = __float2bfloat16(f);
  return __builtin_bit_cast(ushort, h);
}

__device__ __forceinline__ uint pack2(float a, float b) {
  return (uint)f2bf(a) | ((uint)f2bf(b) << 16);
}

// truncating bf16x2 pack in one v_perm_b32
__device__ __forceinline__ uint pack2t(float a, float b) {
  return __builtin_amdgcn_perm(__builtin_bit_cast(uint, b),
                               __builtin_bit_cast(uint, a), 0x07060302u);
}

// single-instruction 2^x (quarter-rate trans pipe); ocml exp2f is ~6 insts
__device__ __forceinline__ float fexp2(float x) {
#if __has_builtin(__builtin_amdgcn_exp2f)
  return __builtin_amdgcn_exp2f(x);
#else
  float r;
  asm volatile("v_exp_f32 %0, %1\n\ts_nop 0" : "=v"(r) : "v"(x));
  return r;
#endif
}

#define CBAR() __asm__ __volatile__("" ::: "memory")

__device__ __forceinline__ void gl2lds16(const ushort* g, ushort* l) {
  __builtin_amdgcn_global_load_lds(
      (const __attribute__((address_space(1))) void*)g,
      (__attribute__((address_space(3))) void*)l, 16, 0, 0);
}

// ------------------------------------------------------------ fp32 -> bf16
__global__ __launch_bounds__(256) void conv_bf16(const float* __restrict__ src,
                                                 ushort* __restrict__ dst,
                                                 int n8) {
  int i = blockIdx.x * 256 + threadIdx.x;
  if (i >= n8) return;
  const float4* s = (const float4*)src + (long)i * 2;
  float4 a = s[0], b = s[1];
  uint4 pk = {pack2(a.x, a.y), pack2(a.z, a.w), pack2(b.x, b.y), pack2(b.z, b.w)};
  ((uint4*)dst)[i] = pk;
}

// ---------------------------------------------------------------- GEMM (NT)
// (unchanged — validated)
__global__ __launch_bounds__(256) void gemm_bt(
    const ushort* __restrict__ A, const ushort* __restrict__ B, int nbn,
    ushort* __restrict__ qb, ushort* __restrict__ kb, ushort* __restrict__ vb,
    float* __restrict__ Cout, int epi) {
  __shared__ __align__(16) ushort As[128 * 64];
  __shared__ __align__(16) ushort Bs[128 * 64];
  const int tid = threadIdx.x;
  const int w = tid >> 6, lane = tid & 63, quad = lane >> 4, lc = lane & 15;
  const int bid = blockIdx.x;
  const int bm = bid / nbn, bn = bid % nbn;
  const int wm = (w & 1) * 64, wn = (w >> 1) * 64;

  f32x4 acc[4][4] = {};

  const ushort* Ag = A + (long)bm * 131072;
  const ushort* Bg = B + (long)bn * 131072;

  for (int k0 = 0; k0 < 1024; k0 += 64) {
    __syncthreads();
    for (int i = 0; i < 4; ++i) {
      int u = i * 256 + tid;
      int row = u >> 3, ch = u & 7;
      gl2lds16(Ag + row * 1024 + k0 + ch * 8, &As[(i * 256 + w * 64) * 8]);
      gl2lds16(Bg + row * 1024 + k0 + ch * 8, &Bs[(i * 256 + w * 64) * 8]);
    }
    __builtin_amdgcn_s_waitcnt(0);
    __syncthreads();
    for (int kc = 0; kc < 2; ++kc) {
      bf16x8 af[4], bfr[4];
      for (int t = 0; t < 4; ++t)
        af[t] = *(const bf16x8*)&As[(wm + t * 16 + lc) * 64 + kc * 32 + quad * 8];
      for (int t = 0; t < 4; ++t)
        bfr[t] = *(const bf16x8*)&Bs[(wn + t * 16 + lc) * 64 + kc * 32 + quad * 8];
      for (int rt = 0; rt < 4; ++rt)
        for (int ct = 0; ct < 4; ++ct)
          acc[rt][ct] = __builtin_amdgcn_mfma_f32_16x16x32_bf16(
              af[rt], bfr[ct], acc[rt][ct], 0, 0, 0);
    }
  }

  const int row0 = bm * 128 + wm;
  if (epi == 0) {
    const int e0 = bn * 128;
    const int g = e0 >> 10;
    const int h = ((e0 & 1023) + wn) >> 6;
    const float qs = (g == 0) ? 0.125f * LOG2E : 1.0f;
    ushort* dst = (g == 0) ? qb : ((g == 1) ? kb : vb);
    const float ang = powf(1e-4f, (float)lc * (1.0f / 15.0f));
    for (int rt = 0; rt < 4; ++rt) {
      for (int r = 0; r < 4; ++r) {
        int m = row0 + rt * 16 + quad * 4 + r;
        int srow = m & 2047;
        int b = m >> 11;
        if (g < 2) {
          float theta = (float)srow * ang;
          float sn, c;
          sincosf(theta, &sn, &c);
          float x1 = acc[rt][0][r], x2 = acc[rt][2][r];
          acc[rt][0][r] = x1 * c - x2 * sn;
          acc[rt][2][r] = x1 * sn + x2 * c;
        }
        ushort* drow = dst + (((long)b * 16 + h) * 2048 + srow) * 64;
        for (int ct = 0; ct < 4; ++ct)
          drow[ct * 16 + lc] = f2bf(acc[rt][ct][r] * qs);
      }
    }
  } else {
    for (int rt = 0; rt < 4; ++rt)
      for (int r = 0; r < 4; ++r) {
        int m = row0 + rt * 16 + quad * 4 + r;
        float* drow = Cout + (long)m * 1024 + bn * 128 + wn;
        for (int ct = 0; ct < 4; ++ct)
          drow[ct * 16 + lc] = acc[rt][ct][r];
      }
  }
}

// ----------------------------------------------------------- V transpose
__global__ __launch_bounds__(256) void vtrans(const ushort* __restrict__ vb,
                                              ushort* __restrict__ vt) {
  __shared__ __align__(16) ushort T[64 * 72];
  const int tid = threadIdx.x, sc = blockIdx.x, bh = blockIdx.y;
  const ushort* src = vb + ((long)bh * 2048 + sc * 64) * 64;
  for (int i = 0; i < 2; ++i) {
    int u = i * 256 + tid;
    int row = u >> 3, ch = u & 7;
    uint4 vv = *(const uint4*)&src[row * 64 + ch * 8];
    const ushort* e = (const ushort*)&vv;
    for (int t = 0; t < 8; ++t) T[(ch * 8 + t) * 72 + row] = e[t];
  }
  __syncthreads();
  for (int i = 0; i < 2; ++i) {
    int u = i * 256 + tid;
    int d = u >> 3, ch = u & 7;
    uint4 vv = *(const uint4*)&T[d * 72 + ch * 8];
    *(uint4*)&vt[((long)bh * 64 + d) * 2048 + sc * 64 + ch * 8] = vv;
  }
}

// ---------------------------------------------------------------- attention
// ONE WAVE PER BLOCK, 32 q-rows. Fixed-max softmax (bias dropped: cancels in
// normalization), per-lane l, parity P. Software-pipelined j-loop, 2x unrolled
// with A/B register ping-pong (no rotate movs). Raw v_exp_f32.
__global__ __launch_bounds__(64) void attn_kernel(
    const ushort* __restrict__ qb, const ushort* __restrict__ kb,
    const ushort* __restrict__ vt, ushort* __restrict__ out) {
  __shared__ __align__(16) ushort Psw2[2][32 * 64];
  const int lane = threadIdx.x;
  const int quad = lane >> 4, lc = lane & 15, l7 = lc & 7;
  const int bid = blockIdx.x;                   // 0..2047
  const int s = 63 - (bid >> 5);                // strip, big-work first
  const int bh = bid & 31;
  const int bidx = bh >> 4, h = bh & 15;
  const int qtbase = s * 32;

  bf16x8 qf[2][2];
  for (int kc = 0; kc < 2; ++kc)
    for (int q2 = 0; q2 < 2; ++q2)
      qf[kc][q2] = *(const bf16x8*)&qb[((long)bh * 2048 + qtbase + q2 * 16 + lc) * 64 +
                                       kc * 32 + quad * 8];

  f32x4 oacc[4][2] = {};
  float l_lane[2] = {0.0f, 0.0f};

  const ushort* K = kb + (long)bh * 131072;
  const ushort* Vt = vt + (long)bh * 131072;
  const int jmax = s >> 1;
  const int rowoff = (s & 1) * 32;
  const int koff = lc * 64 + quad * 8;
  const int voff = lc * 2048 + quad * 8;

#define LOADTILE(KF, VF, JT)                                                   \
  {                                                                            \
    const ushort* Kp_ = K + (JT) * 4096;                                       \
    const ushort* Vp_ = Vt + (JT) * 64;                                        \
    for (int kc = 0; kc < 2; ++kc)                                             \
      for (int t = 0; t < 4; ++t) {                                            \
        KF[kc][t] = *(const bf16x8*)&Kp_[t * 1024 + kc * 32 + koff];           \
        VF[kc][t] = *(const bf16x8*)&Vp_[t * 32768 + kc * 32 + voff];          \
      }                                                                        \
  }

#define COMPUTE(KF, VF, J, PAR)                                                \
  {                                                                            \
    f32x4 sacc[4][2] = {};                                                     \
    for (int kc = 0; kc < 2; ++kc)                                             \
      for (int kt = 0; kt < 4; ++kt)                                           \
        for (int q2 = 0; q2 < 2; ++q2)                                         \
          sacc[kt][q2] = __builtin_amdgcn_mfma_f32_16x16x32_bf16(              \
              KF[kc][kt], qf[kc][q2], sacc[kt][q2], 0, 0, 0);                  \
    if ((J) == jmax) { /* causal partial tile */                               \
      for (int kt = 0; kt < 4; ++kt)                                           \
        for (int q2 = 0; q2 < 2; ++q2) {                                       \
          int rowrel = rowoff + q2 * 16 + lc;                                  \
          for (int r = 0; r < 4; ++r)                                          \
            if (kt * 16 + quad * 4 + r > rowrel) sacc[kt][q2][r] = -1.0e30f;   \
        }                                                                      \
    }                                                                          \
    ushort* Psw = Psw2[PAR];                                                   \
    for (int q2 = 0; q2 < 2; ++q2) {                                           \
      float p[4][4];                                                           \
      float rs = 0.0f;                                                         \
      for (int kt = 0; kt < 4; ++kt)                                           \
        for (int r = 0; r < 4; ++r) {                                          \
          p[kt][r] = fexp2(sacc[kt][q2][r]);                                   \
          rs += p[kt][r];                                                      \
        }                                                                      \
      l_lane[q2] += rs;                                                        \
      for (int kt = 0; kt < 4; ++kt) {                                         \
        uint2 pk = {pack2t(p[kt][0], p[kt][1]), pack2t(p[kt][2], p[kt][3])};   \
        *(uint2*)&Psw[(q2 * 16 + lc) * 64 +                                    \
                      (((kt * 2 + (quad >> 1)) ^ l7) << 3) +                   \
                      ((quad & 1) << 2)] = pk;                                 \
      }                                                                        \
    }                                                                          \
    CBAR(); /* compiler-only: P writes before P reads (HW DS in-order) */      \
    for (int kc = 0; kc < 2; ++kc) {                                           \
      bf16x8 pf[2];                                                            \
      for (int q2 = 0; q2 < 2; ++q2)                                           \
        pf[q2] = *(const bf16x8*)&Psw[(q2 * 16 + lc) * 64 +                    \
                                      (((kc * 4 + quad) ^ l7) << 3)];          \
      for (int mt = 0; mt < 4; ++mt)                                           \
        for (int q2 = 0; q2 < 2; ++q2)                                         \
          oacc[mt][q2] = __builtin_amdgcn_mfma_f32_16x16x32_bf16(              \
              VF[kc][mt], pf[q2], oacc[mt][q2], 0, 0, 0);                      \
    }                                                                          \
  }

  // 2x-unrolled software pipeline: body1 = even j (parity 0) computes A while
  // prefetching B; body2 = odd j (parity 1) computes B while prefetching A.
  bf16x8 kA[2][4], vA[2][4], kB[2][4], vB[2][4];
  LOADTILE(kA, vA, 0);
  int j = 0;
  while (true) {
    int jn = (j < jmax) ? j + 1 : j;
    LOADTILE(kB, vB, jn);
    COMPUTE(kA, vA, j, 0);
    if (j >= jmax) break;
    ++j;
    int jn2 = (j < jmax) ? j + 1 : j;
    LOADTILE(kA, vA, jn2);
    COMPUTE(kB, vB, j, 1);
    if (j >= jmax) break;
    ++j;
  }
#undef LOADTILE
#undef COMPUTE

  // epilogue: reduce l across quads, normalize, store via LDS
  float l_[2];
  for (int q2 = 0; q2 < 2; ++q2) {
    float rs = l_lane[q2];
    rs += __shfl_xor(rs, 16, 64);
    rs += __shfl_xor(rs, 32, 64);
    l_[q2] = rs;
  }
  ushort* Psw = Psw2[0];
  CBAR();
  for (int q2 = 0; q2 < 2; ++q2) {
    float linv = 1.0f / l_[q2];
    for (int mt = 0; mt < 4; ++mt) {
      uint2 pk = {pack2(oacc[mt][q2][0] * linv, oacc[mt][q2][1] * linv),
                  pack2(oacc[mt][q2][2] * linv, oacc[mt][q2][3] * linv)};
      *(uint2*)&Psw[(q2 * 16 + lc) * 64 + (((mt * 2 + (quad >> 1)) ^ l7) << 3) +
                    ((quad & 1) << 2)] = pk;
    }
  }
  CBAR();
  {
    int r2 = lane >> 1;
    long mrow = (long)bidx * 2048 + qtbase + r2;
    for (int c = 0; c < 4; ++c) {
      int c8 = (lane & 1) * 4 + c;
      uint4 vv = *(const uint4*)&Psw[r2 * 64 + ((c8 ^ (r2 & 7)) << 3)];
      *(uint4*)&out[mrow * 1024 + h * 64 + c8 * 8] = vv;
    }
  }
}

extern "C" void kernel_launch(void* const* d_in, const int* in_sizes, int n_in,
                              void* d_out, int out_size, void* d_ws, size_t ws_size,
                              hipStream_t stream) {
  const float* x = nullptr;     // 4194304 elems
  const float* Wqkv = nullptr;  // 3145728 elems
  const float* Wo = nullptr;    // 1048576 elems
  for (int i = 0; i < n_in; ++i) {
    if (in_sizes[i] == 4194304) x = (const float*)d_in[i];
    else if (in_sizes[i] == 3145728) Wqkv = (const float*)d_in[i];
    else if (in_sizes[i] == 1048576) Wo = (const float*)d_in[i];
  }
  float* out = (float*)d_out;  // [4096,1024] fp32 (16 MiB)

  // Workspace (32 MiB) + d_out-as-scratch timeline (same as r13):
  ushort* qbuf = (ushort*)d_ws;
  ushort* kbuf = qbuf + 4194304;
  ushort* vbuf = kbuf + 4194304;
  ushort* vtb  = vbuf + 4194304;
  ushort* wqkvh = vtb;                 // [24..30) before vtrans
  ushort* woh  = qbuf;                 // [0..2) after attn
  ushort* ao   = vbuf;                 // aliases vbuf
  ushort* xh   = (ushort*)d_out;       // x_bf16 in d_out scratch

  conv_bf16<<<2048, 256, 0, stream>>>(x, xh, 524288);
  conv_bf16<<<1536, 256, 0, stream>>>(Wqkv, wqkvh, 393216);
  gemm_bt<<<768, 256, 0, stream>>>(xh, wqkvh, 24, qbuf, kbuf, vbuf, nullptr, 0);
  vtrans<<<dim3(32, 32), 256, 0, stream>>>(vbuf, vtb);
  attn_kernel<<<2048, 64, 0, stream>>>(qbuf, kbuf, vtb, ao);
  conv_bf16<<<512, 256, 0, stream>>>(Wo, woh, 131072);
  gemm_bt<<<256, 256, 0, stream>>>(ao, woh, 8, nullptr, nullptr, nullptr, out, 1);
}

// Round 3
// 198.729 us; speedup vs baseline: 1.2903x; 1.2127x over previous
//
#include <hip/hip_runtime.h>
#include <hip/hip_bf16.h>

// B=2, S=2048, D=1024, H=16, dk=64. INPUTS FP32, OUTPUT FP32. M = 4096 rows.
// ROUND 21: FRAGMENT-MAJOR K/V LAYOUT. Attention was request-rate bound: each
// K/V fragment load touched 16 cache lines at 64 B (row strides 128 B / 4 KB).
// K and V are now stored chunk-contiguous (per (bh,tile): 8 chunks x 1 KB,
// lane-ordered 16-B fragments) so every attn load is 64 lanes x contiguous
// 16 B = 8 full lines. V is written in this layout directly by the QKV GEMM
// epilogue -> vtrans kernel ELIMINATED. Attn math unchanged (r20 body).

typedef __bf16 bf16x8 __attribute__((ext_vector_type(8)));
typedef float f32x4 __attribute__((ext_vector_type(4)));

#define LOG2E 1.4426950408889634f

__device__ __forceinline__ ushort f2bf(float f) {
  __hip_bfloat16 h = __float2bfloat16(f);
  return __builtin_bit_cast(ushort, h);
}

__device__ __forceinline__ uint pack2(float a, float b) {
  return (uint)f2bf(a) | ((uint)f2bf(b) << 16);
}

// truncating bf16x2 pack in one v_perm_b32
__device__ __forceinline__ uint pack2t(float a, float b) {
  return __builtin_amdgcn_perm(__builtin_bit_cast(uint, b),
                               __builtin_bit_cast(uint, a), 0x07060302u);
}

// single-instruction 2^x (quarter-rate trans pipe)
__device__ __forceinline__ float fexp2(float x) {
#if __has_builtin(__builtin_amdgcn_exp2f)
  return __builtin_amdgcn_exp2f(x);
#else
  float r;
  asm volatile("v_exp_f32 %0, %1\n\ts_nop 0" : "=v"(r) : "v"(x));
  return r;
#endif
}

#define CBAR() __asm__ __volatile__("" ::: "memory")

__device__ __forceinline__ void gl2lds16(const ushort* g, ushort* l) {
  __builtin_amdgcn_global_load_lds(
      (const __attribute__((address_space(1))) void*)g,
      (__attribute__((address_space(3))) void*)l, 16, 0, 0);
}

// ------------------------------------------------------------ fp32 -> bf16
__global__ __launch_bounds__(256) void conv_bf16(const float* __restrict__ src,
                                                 ushort* __restrict__ dst,
                                                 int n8) {
  int i = blockIdx.x * 256 + threadIdx.x;
  if (i >= n8) return;
  const float4* s = (const float4*)src + (long)i * 2;
  float4 a = s[0], b = s[1];
  uint4 pk = {pack2(a.x, a.y), pack2(a.z, a.w), pack2(b.x, b.y), pack2(b.z, b.w)};
  ((uint4*)dst)[i] = pk;
}

// ---------------------------------------------------------------- GEMM (NT)
// epi==0: QKV epilogue. Q -> row-major [bh][srow][64] (+rope, log2-scaled).
//         K -> fragment-major KF layout (+rope).
//         V -> fragment-major VF layout (direct; vtrans eliminated).
// epi==1: plain fp32 C row store.
__global__ __launch_bounds__(256) void gemm_bt(
    const ushort* __restrict__ A, const ushort* __restrict__ B, int nbn,
    ushort* __restrict__ qb, ushort* __restrict__ kb, ushort* __restrict__ vb,
    float* __restrict__ Cout, int epi) {
  __shared__ __align__(16) ushort As[128 * 64];
  __shared__ __align__(16) ushort Bs[128 * 64];
  const int tid = threadIdx.x;
  const int w = tid >> 6, lane = tid & 63, quad = lane >> 4, lc = lane & 15;
  const int bid = blockIdx.x;
  const int bm = bid / nbn, bn = bid % nbn;
  const int wm = (w & 1) * 64, wn = (w >> 1) * 64;

  f32x4 acc[4][4] = {};

  const ushort* Ag = A + (long)bm * 131072;
  const ushort* Bg = B + (long)bn * 131072;

  for (int k0 = 0; k0 < 1024; k0 += 64) {
    __syncthreads();
    for (int i = 0; i < 4; ++i) {
      int u = i * 256 + tid;
      int row = u >> 3, ch = u & 7;
      gl2lds16(Ag + row * 1024 + k0 + ch * 8, &As[(i * 256 + w * 64) * 8]);
      gl2lds16(Bg + row * 1024 + k0 + ch * 8, &Bs[(i * 256 + w * 64) * 8]);
    }
    __builtin_amdgcn_s_waitcnt(0);
    __syncthreads();
    for (int kc = 0; kc < 2; ++kc) {
      bf16x8 af[4], bfr[4];
      for (int t = 0; t < 4; ++t)
        af[t] = *(const bf16x8*)&As[(wm + t * 16 + lc) * 64 + kc * 32 + quad * 8];
      for (int t = 0; t < 4; ++t)
        bfr[t] = *(const bf16x8*)&Bs[(wn + t * 16 + lc) * 64 + kc * 32 + quad * 8];
      for (int rt = 0; rt < 4; ++rt)
        for (int ct = 0; ct < 4; ++ct)
          acc[rt][ct] = __builtin_amdgcn_mfma_f32_16x16x32_bf16(
              af[rt], bfr[ct], acc[rt][ct], 0, 0, 0);
    }
  }

  const int row0 = bm * 128 + wm;
  if (epi == 0) {
    const int e0 = bn * 128;
    const int g = e0 >> 10;
    const int h = ((e0 & 1023) + wn) >> 6;
    const float qs = (g == 0) ? 0.125f * LOG2E : 1.0f;
    const float ang = powf(1e-4f, (float)lc * (1.0f / 15.0f));
    for (int rt = 0; rt < 4; ++rt) {
      for (int r = 0; r < 4; ++r) {
        int m = row0 + rt * 16 + quad * 4 + r;
        int srow = m & 2047;
        int b = m >> 11;
        int bh = b * 16 + h;
        if (g < 2) {
          float theta = (float)srow * ang;
          float sn, c;
          sincosf(theta, &sn, &c);
          float x1 = acc[rt][0][r], x2 = acc[rt][2][r];
          acc[rt][0][r] = x1 * c - x2 * sn;
          acc[rt][2][r] = x1 * sn + x2 * c;
        }
        if (g == 0) {
          ushort* drow = qb + (((long)bh) * 2048 + srow) * 64;
          for (int ct = 0; ct < 4; ++ct)
            drow[ct * 16 + lc] = f2bf(acc[rt][ct][r] * qs);
        } else if (g == 1) {
          // KF layout: chunk(kc,t) of tile j; lane = quadK*16 + (srow&15)
          long cb = (((long)bh * 256 + (srow >> 6) * 8 + ((srow >> 4) & 3)) << 9);
          for (int ct = 0; ct < 4; ++ct) {
            int kc = ct >> 1;
            int quadK = (ct & 1) * 2 + (lc >> 3);
            kb[cb + kc * 2048 + (quadK * 16 + (srow & 15)) * 8 + (lc & 7)] =
                f2bf(acc[rt][ct][r]);
          }
        } else {
          // VF layout: chunk(kcV, mt=ct); lane = quadV*16 + lc; elem = srow&7
          long vbase = (((long)bh * 256 + (srow >> 6) * 8 + ((srow >> 5) & 1) * 4)
                        << 9) +
                       ((((srow >> 3) & 3) * 16 + lc) << 3) + (srow & 7);
          for (int ct = 0; ct < 4; ++ct)
            vb[vbase + ct * 512] = f2bf(acc[rt][ct][r]);
        }
      }
    }
  } else {
    for (int rt = 0; rt < 4; ++rt)
      for (int r = 0; r < 4; ++r) {
        int m = row0 + rt * 16 + quad * 4 + r;
        float* drow = Cout + (long)m * 1024 + bn * 128 + wn;
        for (int ct = 0; ct < 4; ++ct)
          drow[ct * 16 + lc] = acc[rt][ct][r];
      }
  }
}

// ---------------------------------------------------------------- attention
// ONE WAVE PER BLOCK, 32 q-rows. r20 body; K/V loads are now fully coalesced
// (fragment-major): each load = 64 lanes x contiguous 16 B (8 full lines).
__global__ __launch_bounds__(64) void attn_kernel(
    const ushort* __restrict__ qb, const ushort* __restrict__ kb,
    const ushort* __restrict__ vt, ushort* __restrict__ out) {
  __shared__ __align__(16) ushort Psw2[2][32 * 64];
  const int lane = threadIdx.x;
  const int quad = lane >> 4, lc = lane & 15, l7 = lc & 7;
  const int bid = blockIdx.x;                   // 0..2047
  const int s = 63 - (bid >> 5);                // strip, big-work first
  const int bh = bid & 31;                      // bh&7 == bid&7 -> XCD-grouped
  const int bidx = bh >> 4, h = bh & 15;
  const int qtbase = s * 32;

  bf16x8 qf[2][2];
  for (int kc = 0; kc < 2; ++kc)
    for (int q2 = 0; q2 < 2; ++q2)
      qf[kc][q2] = *(const bf16x8*)&qb[((long)bh * 2048 + qtbase + q2 * 16 + lc) * 64 +
                                       kc * 32 + quad * 8];

  f32x4 oacc[4][2] = {};
  float l_lane[2] = {0.0f, 0.0f};

  const ushort* K = kb + (long)bh * 131072;
  const ushort* Vt = vt + (long)bh * 131072;
  const int jmax = s >> 1;
  const int rowoff = (s & 1) * 32;
  const int lane8 = lane * 8;

#define LOADTILE(KF, VF, JT)                                                   \
  {                                                                            \
    const ushort* Kp_ = K + (JT) * 4096 + lane8;                               \
    const ushort* Vp_ = Vt + (JT) * 4096 + lane8;                              \
    for (int kc = 0; kc < 2; ++kc)                                             \
      for (int t = 0; t < 4; ++t) {                                            \
        KF[kc][t] = *(const bf16x8*)&Kp_[(kc * 4 + t) * 512];                  \
        VF[kc][t] = *(const bf16x8*)&Vp_[(kc * 4 + t) * 512];                  \
      }                                                                        \
  }

#define COMPUTE(KF, VF, J, PAR)                                                \
  {                                                                            \
    f32x4 sacc[4][2] = {};                                                     \
    for (int kc = 0; kc < 2; ++kc)                                             \
      for (int kt = 0; kt < 4; ++kt)                                           \
        for (int q2 = 0; q2 < 2; ++q2)                                         \
          sacc[kt][q2] = __builtin_amdgcn_mfma_f32_16x16x32_bf16(              \
              KF[kc][kt], qf[kc][q2], sacc[kt][q2], 0, 0, 0);                  \
    if ((J) == jmax) { /* causal partial tile */                               \
      for (int kt = 0; kt < 4; ++kt)                                           \
        for (int q2 = 0; q2 < 2; ++q2) {                                       \
          int rowrel = rowoff + q2 * 16 + lc;                                  \
          for (int r = 0; r < 4; ++r)                                          \
            if (kt * 16 + quad * 4 + r > rowrel) sacc[kt][q2][r] = -1.0e30f;   \
        }                                                                      \
    }                                                                          \
    ushort* Psw = Psw2[PAR];                                                   \
    for (int q2 = 0; q2 < 2; ++q2) {                                           \
      float p[4][4];                                                           \
      float rs = 0.0f;                                                         \
      for (int kt = 0; kt < 4; ++kt)                                           \
        for (int r = 0; r < 4; ++r) {                                          \
          p[kt][r] = fexp2(sacc[kt][q2][r]);                                   \
          rs += p[kt][r];                                                      \
        }                                                                      \
      l_lane[q2] += rs;                                                        \
      for (int kt = 0; kt < 4; ++kt) {                                         \
        uint2 pk = {pack2t(p[kt][0], p[kt][1]), pack2t(p[kt][2], p[kt][3])};   \
        *(uint2*)&Psw[(q2 * 16 + lc) * 64 +                                    \
                      (((kt * 2 + (quad >> 1)) ^ l7) << 3) +                   \
                      ((quad & 1) << 2)] = pk;                                 \
      }                                                                        \
    }                                                                          \
    CBAR(); /* compiler-only: P writes before P reads (HW DS in-order) */      \
    for (int kc = 0; kc < 2; ++kc) {                                           \
      bf16x8 pf[2];                                                            \
      for (int q2 = 0; q2 < 2; ++q2)                                           \
        pf[q2] = *(const bf16x8*)&Psw[(q2 * 16 + lc) * 64 +                    \
                                      (((kc * 4 + quad) ^ l7) << 3)];          \
      for (int mt = 0; mt < 4; ++mt)                                           \
        for (int q2 = 0; q2 < 2; ++q2)                                         \
          oacc[mt][q2] = __builtin_amdgcn_mfma_f32_16x16x32_bf16(              \
              VF[kc][mt], pf[q2], oacc[mt][q2], 0, 0, 0);                      \
    }                                                                          \
  }

  // 2x-unrolled software pipeline with A/B register ping-pong.
  bf16x8 kA[2][4], vA[2][4], kB[2][4], vB[2][4];
  LOADTILE(kA, vA, 0);
  int j = 0;
  while (true) {
    int jn = (j < jmax) ? j + 1 : j;
    LOADTILE(kB, vB, jn);
    COMPUTE(kA, vA, j, 0);
    if (j >= jmax) break;
    ++j;
    int jn2 = (j < jmax) ? j + 1 : j;
    LOADTILE(kA, vA, jn2);
    COMPUTE(kB, vB, j, 1);
    if (j >= jmax) break;
    ++j;
  }
#undef LOADTILE
#undef COMPUTE

  // epilogue: reduce l across quads, normalize, store via LDS
  float l_[2];
  for (int q2 = 0; q2 < 2; ++q2) {
    float rs = l_lane[q2];
    rs += __shfl_xor(rs, 16, 64);
    rs += __shfl_xor(rs, 32, 64);
    l_[q2] = rs;
  }
  ushort* Psw = Psw2[0];
  CBAR();
  for (int q2 = 0; q2 < 2; ++q2) {
    float linv = 1.0f / l_[q2];
    for (int mt = 0; mt < 4; ++mt) {
      uint2 pk = {pack2(oacc[mt][q2][0] * linv, oacc[mt][q2][1] * linv),
                  pack2(oacc[mt][q2][2] * linv, oacc[mt][q2][3] * linv)};
      *(uint2*)&Psw[(q2 * 16 + lc) * 64 + (((mt * 2 + (quad >> 1)) ^ l7) << 3) +
                    ((quad & 1) << 2)] = pk;
    }
  }
  CBAR();
  {
    int r2 = lane >> 1;
    long mrow = (long)bidx * 2048 + qtbase + r2;
    for (int c = 0; c < 4; ++c) {
      int c8 = (lane & 1) * 4 + c;
      uint4 vv = *(const uint4*)&Psw[r2 * 64 + ((c8 ^ (r2 & 7)) << 3)];
      *(uint4*)&out[mrow * 1024 + h * 64 + c8 * 8] = vv;
    }
  }
}

extern "C" void kernel_launch(void* const* d_in, const int* in_sizes, int n_in,
                              void* d_out, int out_size, void* d_ws, size_t ws_size,
                              hipStream_t stream) {
  const float* x = nullptr;     // 4194304 elems
  const float* Wqkv = nullptr;  // 3145728 elems
  const float* Wo = nullptr;    // 1048576 elems
  for (int i = 0; i < n_in; ++i) {
    if (in_sizes[i] == 4194304) x = (const float*)d_in[i];
    else if (in_sizes[i] == 3145728) Wqkv = (const float*)d_in[i];
    else if (in_sizes[i] == 1048576) Wo = (const float*)d_in[i];
  }
  float* out = (float*)d_out;  // [4096,1024] fp32 (16 MiB)

  // Workspace (32 MiB) timeline:
  //  [0,8)   qbuf (Q row-major)          -> later Wo bf16 (woh)
  //  [8,16)  kbuf (K fragment-major)
  //  [16,24) vbuf (V fragment-major, written directly by gemm epilogue)
  //  [24,32) scratch: Wqkv bf16 before/during gemm1 -> attn output (ao) after
  ushort* qbuf = (ushort*)d_ws;
  ushort* kbuf = qbuf + 4194304;
  ushort* vbuf = kbuf + 4194304;
  ushort* scr4 = vbuf + 4194304;
  ushort* wqkvh = scr4;                // Wqkv bf16 [24..30)
  ushort* ao   = scr4;                 // attn out (after gemm1 done with B)
  ushort* woh  = qbuf;                 // Wo bf16 (after attn done with Q)
  ushort* xh   = (ushort*)d_out;       // x_bf16 in d_out scratch

  conv_bf16<<<2048, 256, 0, stream>>>(x, xh, 524288);
  conv_bf16<<<1536, 256, 0, stream>>>(Wqkv, wqkvh, 393216);
  gemm_bt<<<768, 256, 0, stream>>>(xh, wqkvh, 24, qbuf, kbuf, vbuf, nullptr, 0);
  attn_kernel<<<2048, 64, 0, stream>>>(qbuf, kbuf, vbuf, ao);
  conv_bf16<<<512, 256, 0, stream>>>(Wo, woh, 131072);
  gemm_bt<<<256, 256, 0, stream>>>(ao, woh, 8, nullptr, nullptr, nullptr, out, 1);
}

// Round 4
// 196.596 us; speedup vs baseline: 1.3043x; 1.0108x over previous
//
#include <hip/hip_runtime.h>
#include <hip/hip_bf16.h>

// B=2, S=2048, D=1024, H=16, dk=64. INPUTS FP32, OUTPUT FP32. M = 4096 rows.
// ROUND 22: VECTORIZED QKV-GEMM EPILOGUE. r21's epilogue did 64 scattered
// scalar 2-B global stores per thread (8-16 cache lines per wave-store at
// 25-50% coverage). Now: stage the 128x128 bf16 C-tile in LDS (row-major+pad
// for Q/K, transposed for V), one barrier, then 8 fully-coalesced uint4
// global stores per thread (1 KB contiguous per wave-store for K/V chunks).
// Address math is the exact inversion of the validated r21 layouts.

typedef __bf16 bf16x8 __attribute__((ext_vector_type(8)));
typedef float f32x4 __attribute__((ext_vector_type(4)));

#define LOG2E 1.4426950408889634f

__device__ __forceinline__ ushort f2bf(float f) {
  __hip_bfloat16 h = __float2bfloat16(f);
  return __builtin_bit_cast(ushort, h);
}

__device__ __forceinline__ uint pack2(float a, float b) {
  return (uint)f2bf(a) | ((uint)f2bf(b) << 16);
}

// truncating bf16x2 pack in one v_perm_b32
__device__ __forceinline__ uint pack2t(float a, float b) {
  return __builtin_amdgcn_perm(__builtin_bit_cast(uint, b),
                               __builtin_bit_cast(uint, a), 0x07060302u);
}

// single-instruction 2^x (quarter-rate trans pipe)
__device__ __forceinline__ float fexp2(float x) {
#if __has_builtin(__builtin_amdgcn_exp2f)
  return __builtin_amdgcn_exp2f(x);
#else
  float r;
  asm volatile("v_exp_f32 %0, %1\n\ts_nop 0" : "=v"(r) : "v"(x));
  return r;
#endif
}

#define CBAR() __asm__ __volatile__("" ::: "memory")

__device__ __forceinline__ void gl2lds16(const ushort* g, ushort* l) {
  __builtin_amdgcn_global_load_lds(
      (const __attribute__((address_space(1))) void*)g,
      (__attribute__((address_space(3))) void*)l, 16, 0, 0);
}

// ------------------------------------------------------------ fp32 -> bf16
__global__ __launch_bounds__(256) void conv_bf16(const float* __restrict__ src,
                                                 ushort* __restrict__ dst,
                                                 int n8) {
  int i = blockIdx.x * 256 + threadIdx.x;
  if (i >= n8) return;
  const float4* s = (const float4*)src + (long)i * 2;
  float4 a = s[0], b = s[1];
  uint4 pk = {pack2(a.x, a.y), pack2(a.z, a.w), pack2(b.x, b.y), pack2(b.z, b.w)};
  ((uint4*)dst)[i] = pk;
}

// ---------------------------------------------------------------- GEMM (NT)
// epi==0: QKV epilogue via LDS staging + coalesced uint4 stores.
//         Q -> row-major [bh][srow][64] (+rope, log2-scaled)
//         K -> fragment-major KF (+rope);  V -> fragment-major VF.
// epi==1: plain fp32 C row store (unchanged).
__global__ __launch_bounds__(256) void gemm_bt(
    const ushort* __restrict__ A, const ushort* __restrict__ B, int nbn,
    ushort* __restrict__ qb, ushort* __restrict__ kb, ushort* __restrict__ vb,
    float* __restrict__ Cout, int epi) {
  __shared__ __align__(16) ushort SMEM[17408];  // As|Bs (16K) or Ct 128x136
  ushort* As = SMEM;
  ushort* Bs = SMEM + 8192;
  const int tid = threadIdx.x;
  const int w = tid >> 6, lane = tid & 63, quad = lane >> 4, lc = lane & 15;
  const int bid = blockIdx.x;
  const int bm = bid / nbn, bn = bid % nbn;
  const int wm = (w & 1) * 64, wn = (w >> 1) * 64;

  f32x4 acc[4][4] = {};

  const ushort* Ag = A + (long)bm * 131072;
  const ushort* Bg = B + (long)bn * 131072;

  for (int k0 = 0; k0 < 1024; k0 += 64) {
    __syncthreads();
    for (int i = 0; i < 4; ++i) {
      int u = i * 256 + tid;
      int row = u >> 3, ch = u & 7;
      gl2lds16(Ag + row * 1024 + k0 + ch * 8, &As[(i * 256 + w * 64) * 8]);
      gl2lds16(Bg + row * 1024 + k0 + ch * 8, &Bs[(i * 256 + w * 64) * 8]);
    }
    __builtin_amdgcn_s_waitcnt(0);
    __syncthreads();
    for (int kc = 0; kc < 2; ++kc) {
      bf16x8 af[4], bfr[4];
      for (int t = 0; t < 4; ++t)
        af[t] = *(const bf16x8*)&As[(wm + t * 16 + lc) * 64 + kc * 32 + quad * 8];
      for (int t = 0; t < 4; ++t)
        bfr[t] = *(const bf16x8*)&Bs[(wn + t * 16 + lc) * 64 + kc * 32 + quad * 8];
      for (int rt = 0; rt < 4; ++rt)
        for (int ct = 0; ct < 4; ++ct)
          acc[rt][ct] = __builtin_amdgcn_mfma_f32_16x16x32_bf16(
              af[rt], bfr[ct], acc[rt][ct], 0, 0, 0);
    }
  }

  if (epi == 0) {
    const int e0 = bn * 128;
    const int g = e0 >> 10;
    const int h0 = (e0 & 1023) >> 6;  // tile covers heads h0, h0+1
    ushort* Ct = SMEM;                // 128 x 136 staging (aliases As/Bs)
    __syncthreads();                  // all waves done with As/Bs ds_reads

    if (g == 2) {
      // V: transposed staging T[col][row] -> uint2 writes (4 consecutive rows)
      for (int rt = 0; rt < 4; ++rt)
        for (int ct = 0; ct < 4; ++ct) {
          int col = wn + ct * 16 + lc;
          int r0 = wm + rt * 16 + quad * 4;
          uint2 pk = {pack2(acc[rt][ct][0], acc[rt][ct][1]),
                      pack2(acc[rt][ct][2], acc[rt][ct][3])};
          *(uint2*)&Ct[col * 136 + r0] = pk;
        }
    } else {
      // Q/K: rope + row-major staging
      const float qs = (g == 0) ? 0.125f * LOG2E : 1.0f;
      const float ang = powf(1e-4f, (float)lc * (1.0f / 15.0f));
      for (int rt = 0; rt < 4; ++rt)
        for (int r = 0; r < 4; ++r) {
          int row = wm + rt * 16 + quad * 4 + r;
          int srow = (bm * 128 + row) & 2047;
          float theta = (float)srow * ang;
          float sn, c;
          sincosf(theta, &sn, &c);
          float x1 = acc[rt][0][r], x2 = acc[rt][2][r];
          acc[rt][0][r] = x1 * c - x2 * sn;
          acc[rt][2][r] = x1 * sn + x2 * c;
          for (int ct = 0; ct < 4; ++ct)
            Ct[row * 136 + wn + ct * 16 + lc] = f2bf(acc[rt][ct][r] * qs);
        }
    }
    __syncthreads();

    if (g == 0) {
      for (int i = 0; i < 8; ++i) {
        int u = i * 256 + tid;
        int row = u >> 4, c8 = u & 15;
        int m = bm * 128 + row;
        int srow = m & 2047, b = m >> 11;
        uint4 vv = *(const uint4*)&Ct[row * 136 + c8 * 8];
        *(uint4*)&qb[(((long)(b * 16 + h0 + (c8 >> 3))) * 2048 + srow) * 64 +
                     (c8 & 7) * 8] = vv;
      }
    } else if (g == 1) {
      for (int i = 0; i < 8; ++i) {
        int u = i * 256 + tid;
        int head = u >> 10, off = u & 1023;
        int jrel = off >> 9, kc = (off >> 8) & 1, t = (off >> 6) & 3;
        int quadK = (off >> 4) & 3, lcA = off & 15;
        int srl = jrel * 64 + t * 16 + lcA;
        uint4 vv = *(const uint4*)&Ct[srl * 136 + head * 64 + kc * 32 + quadK * 8];
        int m = bm * 128 + srl;
        int srow = m & 2047, b = m >> 11;
        int bh = b * 16 + h0 + head;
        int chunk = (srow >> 6) * 8 + kc * 4 + t;
        *(uint4*)&kb[(long)bh * 131072 + chunk * 512 + (quadK * 16 + lcA) * 8] = vv;
      }
    } else {
      for (int i = 0; i < 8; ++i) {
        int u = i * 256 + tid;
        int head = u >> 10, off = u & 1023;
        int jrel = off >> 9, kcV = (off >> 8) & 1, mt = (off >> 6) & 3;
        int quadV = (off >> 4) & 3, lcA = off & 15;
        int srl = jrel * 64 + kcV * 32 + quadV * 8;
        int d = mt * 16 + lcA;
        uint4 vv = *(const uint4*)&Ct[(head * 64 + d) * 136 + srl];
        int m = bm * 128 + srl;
        int srow = m & 2047, b = m >> 11;
        int bh = b * 16 + h0 + head;
        int chunk = (srow >> 6) * 8 + kcV * 4 + mt;
        *(uint4*)&vb[(long)bh * 131072 + chunk * 512 + (quadV * 16 + lcA) * 8] = vv;
      }
    }
  } else {
    const int row0 = bm * 128 + wm;
    for (int rt = 0; rt < 4; ++rt)
      for (int r = 0; r < 4; ++r) {
        int m = row0 + rt * 16 + quad * 4 + r;
        float* drow = Cout + (long)m * 1024 + bn * 128 + wn;
        for (int ct = 0; ct < 4; ++ct)
          drow[ct * 16 + lc] = acc[rt][ct][r];
      }
  }
}

// ---------------------------------------------------------------- attention
// ONE WAVE PER BLOCK, 32 q-rows. Fragment-major coalesced K/V loads (r21),
// fixed-max softmax with bias dropped, 2x-unrolled A/B register ping-pong.
__global__ __launch_bounds__(64) void attn_kernel(
    const ushort* __restrict__ qb, const ushort* __restrict__ kb,
    const ushort* __restrict__ vt, ushort* __restrict__ out) {
  __shared__ __align__(16) ushort Psw2[2][32 * 64];
  const int lane = threadIdx.x;
  const int quad = lane >> 4, lc = lane & 15, l7 = lc & 7;
  const int bid = blockIdx.x;                   // 0..2047
  const int s = 63 - (bid >> 5);                // strip, big-work first
  const int bh = bid & 31;
  const int bidx = bh >> 4, h = bh & 15;
  const int qtbase = s * 32;

  bf16x8 qf[2][2];
  for (int kc = 0; kc < 2; ++kc)
    for (int q2 = 0; q2 < 2; ++q2)
      qf[kc][q2] = *(const bf16x8*)&qb[((long)bh * 2048 + qtbase + q2 * 16 + lc) * 64 +
                                       kc * 32 + quad * 8];

  f32x4 oacc[4][2] = {};
  float l_lane[2] = {0.0f, 0.0f};

  const ushort* K = kb + (long)bh * 131072;
  const ushort* Vt = vt + (long)bh * 131072;
  const int jmax = s >> 1;
  const int rowoff = (s & 1) * 32;
  const int lane8 = lane * 8;

#define LOADTILE(KF, VF, JT)                                                   \
  {                                                                            \
    const ushort* Kp_ = K + (JT) * 4096 + lane8;                               \
    const ushort* Vp_ = Vt + (JT) * 4096 + lane8;                              \
    for (int kc = 0; kc < 2; ++kc)                                             \
      for (int t = 0; t < 4; ++t) {                                            \
        KF[kc][t] = *(const bf16x8*)&Kp_[(kc * 4 + t) * 512];                  \
        VF[kc][t] = *(const bf16x8*)&Vp_[(kc * 4 + t) * 512];                  \
      }                                                                        \
  }

#define COMPUTE(KF, VF, J, PAR)                                                \
  {                                                                            \
    f32x4 sacc[4][2] = {};                                                     \
    for (int kc = 0; kc < 2; ++kc)                                             \
      for (int kt = 0; kt < 4; ++kt)                                           \
        for (int q2 = 0; q2 < 2; ++q2)                                         \
          sacc[kt][q2] = __builtin_amdgcn_mfma_f32_16x16x32_bf16(              \
              KF[kc][kt], qf[kc][q2], sacc[kt][q2], 0, 0, 0);                  \
    if ((J) == jmax) { /* causal partial tile */                               \
      for (int kt = 0; kt < 4; ++kt)                                           \
        for (int q2 = 0; q2 < 2; ++q2) {                                       \
          int rowrel = rowoff + q2 * 16 + lc;                                  \
          for (int r = 0; r < 4; ++r)                                          \
            if (kt * 16 + quad * 4 + r > rowrel) sacc[kt][q2][r] = -1.0e30f;   \
        }                                                                      \
    }                                                                          \
    ushort* Psw = Psw2[PAR];                                                   \
    for (int q2 = 0; q2 < 2; ++q2) {                                           \
      float p[4][4];                                                           \
      float rs = 0.0f;                                                         \
      for (int kt = 0; kt < 4; ++kt)                                           \
        for (int r = 0; r < 4; ++r) {                                          \
          p[kt][r] = fexp2(sacc[kt][q2][r]);                                   \
          rs += p[kt][r];                                                      \
        }                                                                      \
      l_lane[q2] += rs;                                                        \
      for (int kt = 0; kt < 4; ++kt) {                                         \
        uint2 pk = {pack2t(p[kt][0], p[kt][1]), pack2t(p[kt][2], p[kt][3])};   \
        *(uint2*)&Psw[(q2 * 16 + lc) * 64 +                                    \
                      (((kt * 2 + (quad >> 1)) ^ l7) << 3) +                   \
                      ((quad & 1) << 2)] = pk;                                 \
      }                                                                        \
    }                                                                          \
    CBAR(); /* compiler-only: P writes before P reads (HW DS in-order) */      \
    for (int kc = 0; kc < 2; ++kc) {                                           \
      bf16x8 pf[2];                                                            \
      for (int q2 = 0; q2 < 2; ++q2)                                           \
        pf[q2] = *(const bf16x8*)&Psw[(q2 * 16 + lc) * 64 +                    \
                                      (((kc * 4 + quad) ^ l7) << 3)];          \
      for (int mt = 0; mt < 4; ++mt)                                           \
        for (int q2 = 0; q2 < 2; ++q2)                                         \
          oacc[mt][q2] = __builtin_amdgcn_mfma_f32_16x16x32_bf16(              \
              VF[kc][mt], pf[q2], oacc[mt][q2], 0, 0, 0);                      \
    }                                                                          \
  }

  // 2x-unrolled software pipeline with A/B register ping-pong.
  bf16x8 kA[2][4], vA[2][4], kB[2][4], vB[2][4];
  LOADTILE(kA, vA, 0);
  int j = 0;
  while (true) {
    int jn = (j < jmax) ? j + 1 : j;
    LOADTILE(kB, vB, jn);
    COMPUTE(kA, vA, j, 0);
    if (j >= jmax) break;
    ++j;
    int jn2 = (j < jmax) ? j + 1 : j;
    LOADTILE(kA, vA, jn2);
    COMPUTE(kB, vB, j, 1);
    if (j >= jmax) break;
    ++j;
  }
#undef LOADTILE
#undef COMPUTE

  // epilogue: reduce l across quads, normalize, store via LDS
  float l_[2];
  for (int q2 = 0; q2 < 2; ++q2) {
    float rs = l_lane[q2];
    rs += __shfl_xor(rs, 16, 64);
    rs += __shfl_xor(rs, 32, 64);
    l_[q2] = rs;
  }
  ushort* Psw = Psw2[0];
  CBAR();
  for (int q2 = 0; q2 < 2; ++q2) {
    float linv = 1.0f / l_[q2];
    for (int mt = 0; mt < 4; ++mt) {
      uint2 pk = {pack2(oacc[mt][q2][0] * linv, oacc[mt][q2][1] * linv),
                  pack2(oacc[mt][q2][2] * linv, oacc[mt][q2][3] * linv)};
      *(uint2*)&Psw[(q2 * 16 + lc) * 64 + (((mt * 2 + (quad >> 1)) ^ l7) << 3) +
                    ((quad & 1) << 2)] = pk;
    }
  }
  CBAR();
  {
    int r2 = lane >> 1;
    long mrow = (long)bidx * 2048 + qtbase + r2;
    for (int c = 0; c < 4; ++c) {
      int c8 = (lane & 1) * 4 + c;
      uint4 vv = *(const uint4*)&Psw[r2 * 64 + ((c8 ^ (r2 & 7)) << 3)];
      *(uint4*)&out[mrow * 1024 + h * 64 + c8 * 8] = vv;
    }
  }
}

extern "C" void kernel_launch(void* const* d_in, const int* in_sizes, int n_in,
                              void* d_out, int out_size, void* d_ws, size_t ws_size,
                              hipStream_t stream) {
  const float* x = nullptr;     // 4194304 elems
  const float* Wqkv = nullptr;  // 3145728 elems
  const float* Wo = nullptr;    // 1048576 elems
  for (int i = 0; i < n_in; ++i) {
    if (in_sizes[i] == 4194304) x = (const float*)d_in[i];
    else if (in_sizes[i] == 3145728) Wqkv = (const float*)d_in[i];
    else if (in_sizes[i] == 1048576) Wo = (const float*)d_in[i];
  }
  float* out = (float*)d_out;  // [4096,1024] fp32 (16 MiB)

  // Workspace (32 MiB) timeline:
  //  [0,8)   qbuf (Q row-major)          -> later Wo bf16 (woh)
  //  [8,16)  kbuf (K fragment-major)
  //  [16,24) vbuf (V fragment-major, written directly by gemm epilogue)
  //  [24,32) scratch: Wqkv bf16 before/during gemm1 -> attn output (ao) after
  ushort* qbuf = (ushort*)d_ws;
  ushort* kbuf = qbuf + 4194304;
  ushort* vbuf = kbuf + 4194304;
  ushort* scr4 = vbuf + 4194304;
  ushort* wqkvh = scr4;                // Wqkv bf16 [24..30)
  ushort* ao   = scr4;                 // attn out (after gemm1 done with B)
  ushort* woh  = qbuf;                 // Wo bf16 (after attn done with Q)
  ushort* xh   = (ushort*)d_out;       // x_bf16 in d_out scratch

  conv_bf16<<<2048, 256, 0, stream>>>(x, xh, 524288);
  conv_bf16<<<1536, 256, 0, stream>>>(Wqkv, wqkvh, 393216);
  gemm_bt<<<768, 256, 0, stream>>>(xh, wqkvh, 24, qbuf, kbuf, vbuf, nullptr, 0);
  attn_kernel<<<2048, 64, 0, stream>>>(qbuf, kbuf, vbuf, ao);
  conv_bf16<<<512, 256, 0, stream>>>(Wo, woh, 131072);
  gemm_bt<<<256, 256, 0, stream>>>(ao, woh, 8, nullptr, nullptr, nullptr, out, 1);
}